// Round 8
// baseline (3108.546 us; speedup 1.0000x reference)
//
#include <hip/hip_runtime.h>

// LSTM B=4096, T=512, D=H=25, 3 layers + MLP head + softmax.
// R8 "design C": one wave = 2 batch elements, ZERO barriers.
//   lane = (half = lane>>5 -> batch, u = lane&31 -> unit, active u<25)
//   Each lane owns ALL FOUR gate rows (i=u, f=25+u, g=50+u, o=75+u):
//   cell update is lane-local -> no act exchange, no cross-wave sync.
//   Dot: 13 ds_read_b128 broadcasts of [x(25)|h(25)] per half (2 addrs per
//   wave-instruction = free 2-way broadcast), v_pk_fma over the K dimension
//   in natural {v_j, v_j+1} pairs -> 100 pk_fma, 4 rows x 25 pairs.
//   Weights: 100 f32x2 per lane, loaded once per layer. Layers sequential,
//   h-sequence through ws with 2-step-ahead register prefetch; one
//   s_waitcnt vmcnt(0) per layer boundary (same-wave store->load).
// DS model: 3.15M wave-steps x ~56 DS-cyc / 256 CU ~= 290us (was ~1.6ms).

typedef float f32x2 __attribute__((ext_vector_type(2)));
typedef float f32x4 __attribute__((ext_vector_type(4)));

#define NT 512
#define ND 25

__device__ __forceinline__ float exp2f_(float x){ return __builtin_amdgcn_exp2f(x); }
__device__ __forceinline__ float rcpf_(float x){ return __builtin_amdgcn_rcpf(x); }
__device__ __forceinline__ float sigf(float x){ return rcpf_(1.f + exp2f_(-1.442695041f*x)); }
__device__ __forceinline__ float tanhf_(float x){ return fmaf(2.f, rcpf_(1.f + exp2f_(-2.885390082f*x)), -1.f); }

__device__ __forceinline__ f32x2 mkw(const float* wi, const float* wh, int m){
    const int j0 = 2*m, j1 = 2*m + 1;
    const float e0 = (j0 < ND) ? wi[j0] : wh[j0 - ND];
    const float e1 = (j1 < ND) ? wi[j1] : wh[j1 - ND];
    return (f32x2){e0, e1};
}

#define LO2(v) __builtin_shufflevector(v, v, 0, 1)
#define HI2(v) __builtin_shufflevector(v, v, 2, 3)

#define M25(F) F(0) F(1) F(2) F(3) F(4) F(5) F(6) F(7) F(8) F(9) F(10) F(11) F(12) \
               F(13) F(14) F(15) F(16) F(17) F(18) F(19) F(20) F(21) F(22) F(23) F(24)

#define WDEF(m) f32x2 wI##m = mkw(wiI, whI, m), wF##m = mkw(wiF, whF, m), \
                      wG##m = mkw(wiG, whG, m), wO##m = mkw(wiO, whO, m);

#define PK4(m, V) \
    aI = __builtin_elementwise_fma(wI##m, V, aI); \
    aF = __builtin_elementwise_fma(wF##m, V, aF); \
    aG = __builtin_elementwise_fma(wG##m, V, aG); \
    aO = __builtin_elementwise_fma(wO##m, V, aO);

__global__ __launch_bounds__(256, 2)
void lstm8(const float* __restrict__ xin,
           const float* __restrict__ Wih,
           const float* __restrict__ Whh,
           const float* __restrict__ bih,
           const float* __restrict__ bhh,
           const float* __restrict__ W1p,
           const float* __restrict__ b1p,
           const float* __restrict__ W2p,
           const float* __restrict__ b2p,
           float* __restrict__ out,
           float* __restrict__ ws)
{
    // per wave, per half: [ x(25) | h(25) | 6 pad ] = 56 floats (224 B)
    __shared__ __align__(16) float vec[4][2][56];

    const int wid  = threadIdx.x >> 6;
    const int lane = threadIdx.x & 63;
    const int half = lane >> 5;
    const int u    = lane & 31;                 // unit; active < 25
    const int uc   = (u < ND) ? u : ND - 1;     // clamped for addressing
    const bool act_ = (u < ND);
    const int b    = (blockIdx.x * 4 + wid) * 2 + half;

    float* const myvec = &vec[wid][half][0];
    const f32x4* const vv = (const f32x4*)myvec;

    float hlast = 0.f;   // h_{T-1} of last layer (for head via LDS anyway)

    for (int l = 0; l < 3; ++l) {
        // ---- weight/bias load (once per layer): 4 rows of this unit ----
        const int rI = l * 100 + uc;
        const float* wiI = Wih + (size_t)rI * ND;        const float* whI = Whh + (size_t)rI * ND;
        const float* wiF = Wih + (size_t)(rI + 25) * ND; const float* whF = Whh + (size_t)(rI + 25) * ND;
        const float* wiG = Wih + (size_t)(rI + 50) * ND; const float* whG = Whh + (size_t)(rI + 50) * ND;
        const float* wiO = Wih + (size_t)(rI + 75) * ND; const float* whO = Whh + (size_t)(rI + 75) * ND;
        M25(WDEF)
        const float bI = bih[rI]      + bhh[rI];
        const float bF = bih[rI + 25] + bhh[rI + 25];
        const float bG = bih[rI + 50] + bhh[rI + 50];
        const float bO = bih[rI + 75] + bhh[rI + 75];

        const float* src = (l == 0) ? (xin + (size_t)b * NT * ND)
                                    : (ws  + (size_t)b * NT * ND);
        const float* srcu = src + uc;
        float* const wsb = ws + (size_t)b * NT * ND + uc;

        // ---- init state + 2-deep x prefetch ----
        const float x0v = srcu[0];
        if (act_) { myvec[u] = x0v; myvec[ND + u] = 0.f; }
        float xn1 = srcu[ND];          // x_1
        float xn2 = srcu[2 * ND];      // x_2
        float c = 0.f, h = 0.f;

        for (int t = 0; t < NT; ++t) {
            // ---- dot: 13 broadcast b128 (2 addrs/wave) + 100 v_pk_fma ----
            f32x2 aI = {bI, 0.f}, aF = {bF, 0.f}, aG = {bG, 0.f}, aO = {bO, 0.f};
            f32x4 va = vv[0], vb = vv[1], vc2 = vv[2];
            PK4(0,  LO2(va)) PK4(1,  HI2(va)) va  = vv[3];
            PK4(2,  LO2(vb)) PK4(3,  HI2(vb)) vb  = vv[4];
            PK4(4,  LO2(vc2)) PK4(5, HI2(vc2)) vc2 = vv[5];
            PK4(6,  LO2(va)) PK4(7,  HI2(va)) va  = vv[6];
            PK4(8,  LO2(vb)) PK4(9,  HI2(vb)) vb  = vv[7];
            PK4(10, LO2(vc2)) PK4(11, HI2(vc2)) vc2 = vv[8];
            PK4(12, LO2(va)) PK4(13, HI2(va)) va  = vv[9];
            PK4(14, LO2(vb)) PK4(15, HI2(vb)) vb  = vv[10];
            PK4(16, LO2(vc2)) PK4(17, HI2(vc2)) vc2 = vv[11];
            PK4(18, LO2(va)) PK4(19, HI2(va)) va  = vv[12];
            PK4(20, LO2(vb)) PK4(21, HI2(vb))
            PK4(22, LO2(vc2)) PK4(23, HI2(vc2))
            PK4(24, LO2(va))

            // ---- activations (lane-local: all 4 gates here) ----
            const float si = sigf(aI.x + aI.y);
            const float sf = sigf(aF.x + aF.y);
            const float sg = tanhf_(aG.x + aG.y);
            const float so = sigf(aO.x + aO.y);
            c = fmaf(sf, c, si * sg);
            h = so * tanhf_(c);

            // ---- publish h_t and x_{t+1}; store h for next layer ----
            if (act_) {
                myvec[ND + u] = h;      // in-order DS pipe: safe vs this step's reads
                myvec[u]      = xn1;    // x_{t+1}
                if (l < 2) wsb[(size_t)t * ND] = h;
            }
            xn1 = xn2;
            if (t + 3 < NT) xn2 = srcu[(size_t)(t + 3) * ND];
        }

        // drain ws stores before next layer reads them (same wave, same addrs)
        asm volatile("s_waitcnt vmcnt(0)" ::: "memory");
        hlast = h;
    }
    (void)hlast;

    // ---- head: relu(h W1^T + b1) W2^T + b2, softmax(14). Per half, barrier-free ----
    {
        // W1 gemv: row r1 = u clamped to 16; h read from myvec[25..49] (broadcast)
        const int r1 = (u < 16) ? u : 15;
        float u1 = b1p[r1];
#pragma unroll
        for (int d = 0; d < ND; ++d)
            u1 = fmaf(W1p[r1 * ND + d], myvec[ND + d], u1);
        u1 = fmaxf(u1, 0.f);
        if (u < 16) myvec[u] = u1;          // reuse x area

        const int r2 = (u < 14) ? u : 13;
        float lg = b2p[r2];
#pragma unroll
        for (int k = 0; k < 16; ++k)
            lg = fmaf(W2p[r2 * 16 + k], myvec[k], lg);
        if (u < 14) myvec[ND + u] = lg;     // reuse h area (h consumed above)

        float m = -1e30f;
#pragma unroll
        for (int j = 0; j < 14; ++j) m = fmaxf(m, myvec[ND + j]);
        float s = 0.f;
#pragma unroll
        for (int j = 0; j < 14; ++j)
            s += exp2f_(1.442695041f * (myvec[ND + j] - m));
        const float pr = exp2f_(1.442695041f * (lg - m)) * rcpf_(s);
        if (u < 14) out[b * 14 + u] = pr;
    }
}

extern "C" void kernel_launch(void* const* d_in, const int* in_sizes, int n_in,
                              void* d_out, int out_size, void* d_ws, size_t ws_size,
                              hipStream_t stream)
{
    const float* x   = (const float*)d_in[0];
    const float* Wih = (const float*)d_in[1];
    const float* Whh = (const float*)d_in[2];
    const float* bih = (const float*)d_in[3];
    const float* bhh = (const float*)d_in[4];
    const float* W1  = (const float*)d_in[5];
    const float* b1  = (const float*)d_in[6];
    const float* W2  = (const float*)d_in[7];
    const float* b2  = (const float*)d_in[8];
    float* outp = (float*)d_out;
    float* ws   = (float*)d_ws;   // 4096*512*25*4 = 209,715,200 bytes

    dim3 grid(512), block(256);   // 2048 waves, 2 batches per wave
    hipLaunchKernelGGL(lstm8, grid, block, 0, stream,
                       x, Wih, Whh, bih, bhh, W1, b1, W2, b2, outp, ws);
}

// Round 9
// 2986.146 us; speedup vs baseline: 1.0410x; 1.0410x over previous
//
#include <hip/hip_runtime.h>
#include <cstdint>

// LSTM B=4096, T=512, D=H=25, 3 layers + MLP head + softmax.
// R9: MFMA rewrite. One wave = 16 batches; gates = 7 M-tiles of 16
// INTERLEAVED gate-rows [i0,f0,g0,o0,i1,...] so D's per-lane quad
// (reg r=gate, unit = mtile*4 + lane>>4, batch = lane&15) makes the cell
// update lane-local. K=64 = [x(25)|h(25)|zeros|k63=1.0 (bias col in W)].
// fp32 emulated as f16 hi + 4096*lo, 3 MFMA terms: D1=Whi*Xhi,
// D2=Whi*(4096 Xlo)+(4096 Wlo)*Xhi, D = D1 + D2/4096  (~22-bit mantissa).
// W-frags live in LDS (streamed, 28 b128/step) -> no per-lane weight
// registers -> no AGPR/scratch cliff (R1-R8's wall). h round-trips through
// a 144B-padded LDS [b][k] f16 buffer. Single wave per block: NO barriers.
// Layers sequential via ws packed {hi,lo} u32. 256 blocks x 64 thr.
// Frag layout assumptions (m89-verified C/D; A/B symmetric k-major):
//   A: lane holds A[m=lane&15][k=(lane>>4)*8+i]   (8 f16 = 1 b128)
//   B: lane holds B[n=lane&15][k=(lane>>4)*8+i]   (XH stored [b][k])
//   D: lane holds D[m=(lane>>4)*4+r][n=lane&15]

typedef _Float16 f16;
typedef f16  f16x8 __attribute__((ext_vector_type(8)));
typedef float f32x4 __attribute__((ext_vector_type(4)));

#define NT 512
#define ND 25
#define LOSCALE 4096.0f
#define INVLO   2.44140625e-4f

__device__ __forceinline__ float exp2f_(float x){ return __builtin_amdgcn_exp2f(x); }
__device__ __forceinline__ float rcpf_(float x){ return __builtin_amdgcn_rcpf(x); }
__device__ __forceinline__ float sigf(float x){ return rcpf_(1.f + exp2f_(-1.442695041f*x)); }
__device__ __forceinline__ float tanhf_(float x){ return fmaf(2.f, rcpf_(1.f + exp2f_(-2.885390082f*x)), -1.f); }

__device__ __forceinline__ unsigned short f16b(f16 h){ union{f16 h; unsigned short s;} u; u.h=h; return u.s; }
__device__ __forceinline__ f16 b2f16(unsigned short s){ union{f16 h; unsigned short s;} u; u.s=s; return u.h; }

#define MFMA(a,b,c) __builtin_amdgcn_mfma_f32_16x16x32_f16((a),(b),(c),0,0,0)

__global__ __launch_bounds__(64, 1)
void lstm9(const float* __restrict__ xin,
           const float* __restrict__ Wih,
           const float* __restrict__ Whh,
           const float* __restrict__ bih,
           const float* __restrict__ bhh,
           const float* __restrict__ W1,
           const float* __restrict__ b1,
           const float* __restrict__ W2,
           const float* __restrict__ b2,
           float* __restrict__ out,
           uint32_t* __restrict__ ws)
{
    // W fragment store: 14 blocks (mt*2+kt) x 64 lanes x 8 f16
    __shared__ __align__(16) f16 WH[14*64*8];
    __shared__ __align__(16) f16 WL[14*64*8];
    // XH: [16 batches][72 f16] (144B row: k 0..63 data, 64..71 pad)
    __shared__ __align__(16) f16 XH_H[16*72];
    __shared__ __align__(16) f16 XH_L[16*72];
    __shared__ __align__(16) float hfin[16*28];

    const int L  = threadIdx.x;      // single wave
    const int bq = L & 15;           // batch-in-tile; also frag row index
    const int lg = L >> 4;
    const int bb = blockIdx.x * 16;  // global batch base

    // ---- one-time init: zero XH, set bias column ----
    for (int i = L; i < 16*72; i += 64) { XH_H[i] = (f16)0.f; XH_L[i] = (f16)0.f; }
    if (L < 16) XH_H[L*72 + 63] = (f16)1.f;

    float c0,c1,c2,c3,c4,c5,c6;
    float h0=0,h1=0,h2=0,h3=0,h4=0,h5=0,h6=0;

    for (int l = 0; l < 3; ++l) {
        // wait for prev layer's ws stores before any reads of them
        asm volatile("s_waitcnt vmcnt(0)" ::: "memory");

        // ---- build W fragments (hi + 4096*lo f16) into LDS ----
        for (int blk = 0; blk < 14; ++blk) {
            const int mt = blk >> 1, kt = blk & 1;
            const int rp = mt*16 + bq;            // interleaved row: unit=rp>>2, gate=rp&3
            const int u  = rp >> 2, g = rp & 3;
            const int ro = g*25 + u;              // original row (torch i,f,g,o blocks)
            f16x8 vh, vl;
#pragma unroll
            for (int i = 0; i < 8; ++i) {
                const int k = kt*32 + lg*8 + i;
                float w = 0.f;
                if (rp < 100) {
                    if (k < 25)       w = Wih[((size_t)l*100 + ro)*25 + k];
                    else if (k < 50)  w = Whh[((size_t)l*100 + ro)*25 + (k-25)];
                    else if (k == 63) w = bih[l*100 + ro] + bhh[l*100 + ro];
                }
                const f16 hi = (f16)w;
                vh[i] = hi;
                vl[i] = (f16)((w - (float)hi) * LOSCALE);
            }
            *(f16x8*)&WH[blk*512 + L*8] = vh;
            *(f16x8*)&WL[blk*512 + L*8] = vl;
        }

        const bool isl0 = (l == 0);
        const float*    srcx = xin + (size_t)(bb)*NT*ND;
        const uint32_t* srcw = ws  + (size_t)(bb)*NT*ND;

        // ---- per-layer state init: c=h=0, XH h-region=0, x0 staged ----
        c0=c1=c2=c3=c4=c5=c6=0.f;
#pragma unroll
        for (int j = 0; j < 7; ++j) {
            const int u = lg + 4*j;
            if (u < 25) {
                XH_H[bq*72 + 25 + u] = (f16)0.f;
                XH_L[bq*72 + 25 + u] = (f16)0.f;
                f16 hi, lo;
                if (isl0) {
                    const float v = srcx[((size_t)bq*NT + 0)*ND + u];
                    hi = (f16)v; lo = (f16)((v - (float)hi) * LOSCALE);
                } else {
                    const uint32_t p = srcw[((size_t)bq*NT + 0)*ND + u];
                    hi = b2f16((unsigned short)(p & 0xffff));
                    lo = b2f16((unsigned short)(p >> 16));
                }
                XH_H[bq*72 + u] = hi;
                XH_L[bq*72 + u] = lo;
            }
        }

        for (int t = 0; t < NT; ++t) {
            // ---- B-fragments for this step ----
            const f16x8 bh0 = *(const f16x8*)&XH_H[bq*72 +  0 + lg*8];
            const f16x8 bh1 = *(const f16x8*)&XH_H[bq*72 + 32 + lg*8];
            const f16x8 bl0 = *(const f16x8*)&XH_L[bq*72 +  0 + lg*8];
            const f16x8 bl1 = *(const f16x8*)&XH_L[bq*72 + 32 + lg*8];

            // ---- prefetch next-step input (used at end of iter) ----
            float    xnf0=0,xnf1=0,xnf2=0,xnf3=0,xnf4=0,xnf5=0,xnf6=0;
            uint32_t xnp0=0,xnp1=0,xnp2=0,xnp3=0,xnp4=0,xnp5=0,xnp6=0;
            if (t + 1 < NT) {
#pragma unroll
                for (int j = 0; j < 7; ++j) {
                    const int u = lg + 4*j;
                    if (u < 25) {
                        if (isl0) {
                            const float v = srcx[((size_t)bq*NT + (t+1))*ND + u];
                            if (j==0) xnf0=v; else if (j==1) xnf1=v; else if (j==2) xnf2=v;
                            else if (j==3) xnf3=v; else if (j==4) xnf4=v; else if (j==5) xnf5=v; else xnf6=v;
                        } else {
                            const uint32_t p = srcw[((size_t)bq*NT + (t+1))*ND + u];
                            if (j==0) xnp0=p; else if (j==1) xnp1=p; else if (j==2) xnp2=p;
                            else if (j==3) xnp3=p; else if (j==4) xnp4=p; else if (j==5) xnp5=p; else xnp6=p;
                        }
                    }
                }
            }

            // ---- 42 MFMA: D1 = Whi*Xhi ; D2 = Whi*(4096 Xlo) + (4096 Wlo)*Xhi ----
            f32x4 d1_0={0,0,0,0},d1_1={0,0,0,0},d1_2={0,0,0,0},d1_3={0,0,0,0},
                  d1_4={0,0,0,0},d1_5={0,0,0,0},d1_6={0,0,0,0};
            f32x4 d2_0={0,0,0,0},d2_1={0,0,0,0},d2_2={0,0,0,0},d2_3={0,0,0,0},
                  d2_4={0,0,0,0},d2_5={0,0,0,0},d2_6={0,0,0,0};
#define DO_MT(mt, D1, D2)                                                     \
            {                                                                  \
                const f16x8 wh0 = *(const f16x8*)&WH[(mt*2+0)*512 + L*8];      \
                const f16x8 wh1 = *(const f16x8*)&WH[(mt*2+1)*512 + L*8];      \
                const f16x8 wl0 = *(const f16x8*)&WL[(mt*2+0)*512 + L*8];      \
                const f16x8 wl1 = *(const f16x8*)&WL[(mt*2+1)*512 + L*8];      \
                D1 = MFMA(wh0, bh0, D1);  D1 = MFMA(wh1, bh1, D1);             \
                D2 = MFMA(wh0, bl0, D2);  D2 = MFMA(wh1, bl1, D2);             \
                D2 = MFMA(wl0, bh0, D2);  D2 = MFMA(wl1, bh1, D2);             \
            }
            DO_MT(0, d1_0, d2_0) DO_MT(1, d1_1, d2_1) DO_MT(2, d1_2, d2_2)
            DO_MT(3, d1_3, d2_3) DO_MT(4, d1_4, d2_4) DO_MT(5, d1_5, d2_5)
            DO_MT(6, d1_6, d2_6)
#undef DO_MT

            // ---- activations + cell update (lane-local quads) ----
#define DO_UPD(D1, D2, C, H)                                                  \
            {                                                                  \
                const f32x4 dd = D1 + D2 * INVLO;                              \
                const float gi = sigf(dd[0]);                                  \
                const float gf = sigf(dd[1]);                                  \
                const float gg = tanhf_(dd[2]);                                \
                const float go = sigf(dd[3]);                                  \
                C = fmaf(gf, C, gi * gg);                                      \
                H = go * tanhf_(C);                                            \
            }
            DO_UPD(d1_0, d2_0, c0, h0) DO_UPD(d1_1, d2_1, c1, h1)
            DO_UPD(d1_2, d2_2, c2, h2) DO_UPD(d1_3, d2_3, c3, h3)
            DO_UPD(d1_4, d2_4, c4, h4) DO_UPD(d1_5, d2_5, c5, h5)
            DO_UPD(d1_6, d2_6, c6, h6)
#undef DO_UPD

            // ---- publish h_t (hi/lo) + ws store; stage x_{t+1} ----
#pragma unroll
            for (int j = 0; j < 7; ++j) {
                const int u = 4*j + lg;          // unit of h{j} on this lane
                if (u < 25) {
                    const float hv = (j==0)?h0:(j==1)?h1:(j==2)?h2:(j==3)?h3:(j==4)?h4:(j==5)?h5:h6;
                    const f16 hi = (f16)hv;
                    const f16 lo = (f16)((hv - (float)hi) * LOSCALE);
                    XH_H[bq*72 + 25 + u] = hi;
                    XH_L[bq*72 + 25 + u] = lo;
                    if (l < 2) {
                        const uint32_t p = (uint32_t)f16b(hi) | ((uint32_t)f16b(lo) << 16);
                        ws[((size_t)(bb+bq)*NT + t)*ND + u] = p;
                    }
                }
            }
            if (t + 1 < NT) {
#pragma unroll
                for (int j = 0; j < 7; ++j) {
                    const int u = lg + 4*j;
                    if (u < 25) {
                        f16 hi, lo;
                        if (isl0) {
                            const float v = (j==0)?xnf0:(j==1)?xnf1:(j==2)?xnf2:(j==3)?xnf3:(j==4)?xnf4:(j==5)?xnf5:xnf6;
                            hi = (f16)v; lo = (f16)((v - (float)hi) * LOSCALE);
                        } else {
                            const uint32_t p = (j==0)?xnp0:(j==1)?xnp1:(j==2)?xnp2:(j==3)?xnp3:(j==4)?xnp4:(j==5)?xnp5:xnp6;
                            hi = b2f16((unsigned short)(p & 0xffff));
                            lo = b2f16((unsigned short)(p >> 16));
                        }
                        XH_H[bq*72 + u] = hi;
                        XH_L[bq*72 + u] = lo;
                    }
                }
            }
        } // t
    } // l

    // ---- head: relu(h W1^T + b1) W2^T + b2, softmax(14) ----
#pragma unroll
    for (int j = 0; j < 7; ++j) {
        const int u = 4*j + lg;
        if (u < 25) {
            const float hv = (j==0)?h0:(j==1)?h1:(j==2)?h2:(j==3)?h3:(j==4)?h4:(j==5)?h5:h6;
            hfin[bq*28 + u] = hv;
        }
    }
    // single wave: DS is in-order; compiler inserts lgkmcnt before dependent reads
    if (L < 16) {
        const int b = L;
        float u1[16];
#pragma unroll
        for (int r = 0; r < 16; ++r) {
            float acc = b1[r];
#pragma unroll
            for (int d = 0; d < 25; ++d) acc = fmaf(W1[r*25 + d], hfin[b*28 + d], acc);
            u1[r] = fmaxf(acc, 0.f);
        }
        float lgt[14]; float m = -1e30f;
#pragma unroll
        for (int r = 0; r < 14; ++r) {
            float acc = b2[r];
#pragma unroll
            for (int k = 0; k < 16; ++k) acc = fmaf(W2[r*16 + k], u1[k], acc);
            lgt[r] = acc; m = fmaxf(m, acc);
        }
        float s = 0.f;
#pragma unroll
        for (int r = 0; r < 14; ++r) { lgt[r] = exp2f_(1.442695041f*(lgt[r]-m)); s += lgt[r]; }
        const float inv = rcpf_(s);
#pragma unroll
        for (int r = 0; r < 14; ++r) out[(size_t)(bb+b)*14 + r] = lgt[r]*inv;
    }
}

extern "C" void kernel_launch(void* const* d_in, const int* in_sizes, int n_in,
                              void* d_out, int out_size, void* d_ws, size_t ws_size,
                              hipStream_t stream)
{
    const float* x   = (const float*)d_in[0];
    const float* Wih = (const float*)d_in[1];
    const float* Whh = (const float*)d_in[2];
    const float* bih = (const float*)d_in[3];
    const float* bhh = (const float*)d_in[4];
    const float* W1  = (const float*)d_in[5];
    const float* b1  = (const float*)d_in[6];
    const float* W2  = (const float*)d_in[7];
    const float* b2  = (const float*)d_in[8];
    float*    outp = (float*)d_out;
    uint32_t* ws   = (uint32_t*)d_ws;   // 4096*512*25*4 B = 210 MB (packed f16 hi/lo)

    dim3 grid(4096 / 16), block(64);    // 256 blocks, 1 wave each
    hipLaunchKernelGGL(lstm9, grid, block, 0, stream,
                       x, Wih, Whh, bih, bhh, W1, b1, W2, b2, outp, ws);
}